// Round 14
// baseline (995.633 us; speedup 1.0000x reference)
//
#include <hip/hip_runtime.h>
#include <stdint.h>

typedef unsigned int u32;
using i32x4 = __attribute__((ext_vector_type(4))) int;

// async global->LDS, 16B per lane, dest = wave-uniform base + lane*16
#define GLD_LDS16(SRC, DST)                                      \
  __builtin_amdgcn_global_load_lds(                              \
      (const __attribute__((address_space(1))) void*)(SRC),      \
      (__attribute__((address_space(3))) void*)(DST), 16, 0, 0)

#define SCHED0() __builtin_amdgcn_sched_barrier(0)
#define BAR()    __builtin_amdgcn_s_barrier()

// ---------- pass 1: per-row symmetric int8 quant (x rows, then w rows) ----------
__global__ __launch_bounds__(256)
void quant_rows(const float* __restrict__ x, const float* __restrict__ w,
                signed char* __restrict__ xq, signed char* __restrict__ wq,
                float* __restrict__ sx, float* __restrict__ sw,
                int Mrows, int totRows, int K) {
  __shared__ float red[4];
  for (int row = blockIdx.x; row < totRows; row += gridDim.x) {
    const bool isx = row < Mrows;
    const float* src = isx ? x + (size_t)row * K : w + (size_t)(row - Mrows) * K;
    const float4* s4 = reinterpret_cast<const float4*>(src) + threadIdx.x * 4;
    float4 v[4];
#pragma unroll
    for (int g = 0; g < 4; ++g) v[g] = s4[g];
    float am = 0.f;
#pragma unroll
    for (int g = 0; g < 4; ++g)
      am = fmaxf(am, fmaxf(fmaxf(fabsf(v[g].x), fabsf(v[g].y)),
                           fmaxf(fabsf(v[g].z), fabsf(v[g].w))));
#pragma unroll
    for (int m = 1; m <= 32; m <<= 1) am = fmaxf(am, __shfl_xor(am, m));
    if ((threadIdx.x & 63) == 0) red[threadIdx.x >> 6] = am;
    __syncthreads();
    am = fmaxf(fmaxf(red[0], red[1]), fmaxf(red[2], red[3]));
    const float s   = am > 0.f ? am * (1.f / 127.f) : 1.f;
    const float inv = am > 0.f ? 127.f / am : 0.f;
    u32 pk[4];
#pragma unroll
    for (int g = 0; g < 4; ++g) {
      const float* vp = reinterpret_cast<const float*>(&v[g]);
      u32 p = 0;
#pragma unroll
      for (int e = 0; e < 4; ++e) {
        int q = (int)rintf(vp[e] * inv);
        q = q < -127 ? -127 : (q > 127 ? 127 : q);
        p |= ((u32)(q & 0xff)) << (8 * e);
      }
      pk[g] = p;
    }
    signed char* dst = (isx ? xq + (size_t)row * K : wq + (size_t)(row - Mrows) * K)
                       + threadIdx.x * 16;
    *reinterpret_cast<uint4*>(dst) = make_uint4(pk[0], pk[1], pk[2], pk[3]);
    if (threadIdx.x == 0) { if (isx) sx[row] = s; else sw[row - Mrows] = s; }
    __syncthreads();
  }
}

// ---------- pass 2: int8 GEMM BK=128, B DIRECT-FROM-L2 (registers), A in LDS ----------
// The serial law tile = LDS_wall + MFMA_wall survived 6 schedule permutations (r3..r13),
// so this round REMOVES work from the LDS pipe: B fragments are loaded global->VGPR
// (per-lane fragment-pattern addresses, no swizzle, no barriers), double-buffered in
// registers one full tile ahead. LDS holds only A: [2][256*128] = 64 KiB, same verified
// XOR swizzle (0 conflicts). LDS wall 2304 -> 1536 cyc/CU-tile.
// XCD map is nt-MAJOR so the ~32 concurrent wgs of an XCD share ONE 1MB B panel
// (L2-resident): xcd=bid&7, j=bid>>3, nt=xcd*8+(j>>5), mt=j&31 (bijective, 2048 wgs).
// Per tile (2 barriers):
//   gate vmcnt(4) | BAR1 | issue B(t+1)->BFN (8 global_load_dwordx4)
//   | rd afA(mh0 k0) C1=afA*BF[0-3] | rd afB(mh1 k0) C2 | rd afA(mh0 k1) C3=..BF[4-7]
//   | rd afB(mh1 k1) C4 | BAR2 (all waves' A(t) reads retired via C4's lgkm gate)
//   | stage A(t+2)->lds[cur] (4 gloads)
// Ledger: queue at tile-t gate = [A(t):4 (staged t-2 end), B(t):8 (issued t-1 start),
// A(t+1):4 (staged t-1 end)] -> vmcnt(4) drains A(t)+B(t), both >=1 full tile old.
// BAR1 publishes A(t) cross-wave. WAR: stage after BAR2; BFN regs dead since C4(t-1).
__global__ __launch_bounds__(512, 2)
void gemm_i8_bdir(const signed char* __restrict__ A,   // [M][K] i8
                  const signed char* __restrict__ B,   // [N][K] i8
                  const float* __restrict__ sx,        // [M]
                  const float* __restrict__ sw,        // [N]
                  const float* __restrict__ wscale_p,  // [1]
                  const float* __restrict__ bias,      // [N]
                  float* __restrict__ C,               // [M][N] fp32
                  int Nn, int Kk) {
  __shared__ signed char lds[2][256 * 128];   // A only, 64 KiB

  const int tid  = threadIdx.x;
  const int lane = tid & 63;
  const int wave = tid >> 6;       // 0..7
  const int wr = wave >> 2;        // 0..1 (M)
  const int wc = wave & 3;         // 0..3 (N)

  // nt-major XCD map: each XCD's concurrent wgs share one B panel (L2-resident)
  const int bid = blockIdx.x;
  const int xcd = bid & 7;
  const int j   = bid >> 3;        // 0..255
  const int nt  = xcd * 8 + (j >> 5);
  const int mt  = j & 31;
  const int m0 = mt * 256, n0 = nt * 256;

  // A staging: per gload instr, 64 lanes = 8 rows x 128B; lane l -> row l>>3, slot l&7
  const int srow = lane >> 3;
  const int ss   = (lane & 7) ^ (srow & 7);   // inverse-swizzled source k-slot
  const int r16  = lane & 15;
  const int kq   = lane >> 4;

  const signed char* ga = A + ((size_t)m0 + wave * 32 + srow) * Kk + ss * 16;
  // B direct: lane reads row n0+wc*64+ni*16+r16, bytes kq*16 + ks*64 of each k-tile
  const signed char* gBb = B + ((size_t)n0 + wc * 64 + r16) * Kk + (kq << 4);

  // A fragment byte offsets in LDS: row*128 + ((kq ^ (row&7))<<4); ks flips bit 6
  const int aoff = (wr * 128 + r16) * 128 + ((kq ^ (r16 & 7)) << 4);

  i32x4 acc[8][4];
#pragma unroll
  for (int i = 0; i < 8; ++i)
#pragma unroll
    for (int jj = 0; jj < 4; ++jj)
      acc[i][jj] = (i32x4){0, 0, 0, 0};

  i32x4 afA[4], afB[4];    // A frags (mh roles, rotating ks)
  i32x4 bfP[8], bfQ[8];    // B frags [ni*2+ks... laid out ks-major: 0-3=ks0,4-7=ks1]

#define STAGEA(bfi_, kt_) do {                                                  \
    const signed char* _g = ga + (size_t)(kt_) * 128;                           \
    signed char* _d = &lds[bfi_][wave * 32 * 128];                              \
    GLD_LDS16(_g,                    _d);                                       \
    GLD_LDS16(_g + (size_t)8  * Kk,  _d + 1024);                                \
    GLD_LDS16(_g + (size_t)16 * Kk,  _d + 2048);                                \
    GLD_LDS16(_g + (size_t)24 * Kk,  _d + 3072);                                \
  } while (0)

#define LOADB(BF_, kt_) do {                                                    \
    const signed char* _b = gBb + (size_t)(kt_) * 128;                          \
    _Pragma("unroll") for (int _n = 0; _n < 4; ++_n) {                          \
      BF_[_n]     = *reinterpret_cast<const i32x4*>(_b + (size_t)(_n * 16) * Kk);      \
      BF_[4 + _n] = *reinterpret_cast<const i32x4*>(_b + (size_t)(_n * 16) * Kk + 64); \
    } } while (0)

#define LDFA(AF_, la_, mh_, ks_) do {                                           \
    _Pragma("unroll") for (int _i = 0; _i < 4; ++_i)                            \
      AF_[_i] = *reinterpret_cast<const i32x4*>(                                \
          (la_) + ((aoff + ((mh_) * 4 + _i) * 2048) ^ ((ks_) << 6)));           \
  } while (0)

#define MFMAC(mh_, AF_, BF_, kb_)                                               \
  _Pragma("unroll") for (int _i = 0; _i < 4; ++_i)                              \
  _Pragma("unroll") for (int _n = 0; _n < 4; ++_n)                              \
    acc[(mh_) * 4 + _i][_n] = __builtin_amdgcn_mfma_i32_16x16x64_i8(            \
        AF_[_i], BF_[(kb_) * 4 + _n], acc[(mh_) * 4 + _i][_n], 0, 0, 0)

  const int KT = Kk >> 7;   // 32

  // ---- prologue: A(t0)->buf0 ; B(t0)->bfP ; A(t1)->buf1  (no wait: tile0's gate) ----
  STAGEA(0, 0);
  LOADB(bfP, 0);
  STAGEA(1, 1);

#define TILE(t_, CUR_, BF_, BFN_) do {                                          \
    const signed char* laC = &lds[CUR_][0];                                     \
    const int kt1 = ((t_) + 1 < KT) ? (t_) + 1 : KT - 1;                        \
    const int kt2 = ((t_) + 2 < KT) ? (t_) + 2 : KT - 1;                        \
    asm volatile("s_waitcnt vmcnt(4)" ::: "memory");  /* A(t)+B(t) landed */    \
    SCHED0(); BAR(); SCHED0();                                                  \
    LOADB(BFN_, kt1);                         /* B(t+1) -> regs, 8 gloads */    \
    LDFA(afA, laC, 0, 0);                                                       \
    MFMAC(0, afA, BF_, 0);                    /* C1: mh0 ks0 */                 \
    LDFA(afB, laC, 1, 0);                                                       \
    MFMAC(1, afB, BF_, 0);                    /* C2: mh1 ks0 */                 \
    LDFA(afA, laC, 0, 1);                                                       \
    MFMAC(0, afA, BF_, 1);                    /* C3: mh0 ks1 */                 \
    LDFA(afB, laC, 1, 1);                                                       \
    MFMAC(1, afB, BF_, 1);                    /* C4: mh1 ks1 */                 \
    SCHED0(); BAR(); SCHED0();                /* all A(t) reads retired */      \
    STAGEA(CUR_, kt2);                        /* A(t+2) -> lds[cur] */          \
  } while (0)

  for (int t = 0; t < KT; t += 2) {
    TILE(t,     0, bfP, bfQ);
    TILE(t + 1, 1, bfQ, bfP);
  }

  // ---- epilogue: out = acc * sx[row] * (sw[col]*wscale) + bias ----
  const float wsc = wscale_p[0];
  float cw[4], bv[4];
#pragma unroll
  for (int ni = 0; ni < 4; ++ni) {
    const int col = n0 + wc * 64 + ni * 16 + r16;
    cw[ni] = sw[col] * wsc;
    bv[ni] = bias[col];
  }
#pragma unroll
  for (int mi = 0; mi < 8; ++mi) {
#pragma unroll
    for (int r = 0; r < 4; ++r) {
      // C/D layout (16x16 shapes, dtype-independent): col = lane&15, row = (lane>>4)*4 + reg
      const int row = m0 + wr * 128 + mi * 16 + kq * 4 + r;
      const float sxr = sx[row];
      float* cp = C + (size_t)row * Nn + (n0 + wc * 64 + r16);
#pragma unroll
      for (int ni = 0; ni < 4; ++ni)
        cp[ni * 16] = (float)acc[mi][ni][r] * (sxr * cw[ni]) + bv[ni];
    }
  }
#undef STAGEA
#undef LOADB
#undef LDFA
#undef MFMAC
#undef TILE
}

extern "C" void kernel_launch(void* const* d_in, const int* in_sizes, int n_in,
                              void* d_out, int out_size, void* d_ws, size_t ws_size,
                              hipStream_t stream) {
  (void)n_in; (void)out_size; (void)ws_size;
  const float* x  = (const float*)d_in[0];   // [M][K] fp32
  const float* w  = (const float*)d_in[1];   // [N][K] fp32 (fp8-representable values)
  const float* sc = (const float*)d_in[2];   // [1]
  const float* bs = (const float*)d_in[3];   // [N]
  float* out = (float*)d_out;                // [M][N] fp32

  const int N = in_sizes[3];        // 16384
  const int K = in_sizes[1] / N;    // 4096
  const int M = in_sizes[0] / K;    // 8192

  signed char* xq = (signed char*)d_ws;            // [M][K] i8  (32 MB)
  signed char* wq = xq + (size_t)M * K;            // [N][K] i8  (64 MB)
  float* sxp = (float*)(wq + (size_t)N * K);       // [M]
  float* swp = sxp + M;                            // [N]

  quant_rows<<<M + N, 256, 0, stream>>>(x, w, xq, wq, sxp, swp, M, M + N, K);

  const int nwg = (M / 256) * (N / 256);           // 2048 = 8 XCD x 256
  gemm_i8_bdir<<<nwg, 512, 0, stream>>>(xq, wq, sxp, swp, sc, bs, out, N, K);
}

// Round 16
// 764.611 us; speedup vs baseline: 1.3021x; 1.3021x over previous
//
#include <hip/hip_runtime.h>
#include <stdint.h>

typedef unsigned int u32;
using i32x4 = __attribute__((ext_vector_type(4))) int;

// async global->LDS, 16B per lane, dest = wave-uniform base + lane*16
#define GLD_LDS16(SRC, DST)                                      \
  __builtin_amdgcn_global_load_lds(                              \
      (const __attribute__((address_space(1))) void*)(SRC),      \
      (__attribute__((address_space(3))) void*)(DST), 16, 0, 0)

#define SCHED0() __builtin_amdgcn_sched_barrier(0)
#define BAR()    __builtin_amdgcn_s_barrier()
#define CFENCE() asm volatile("" ::: "memory")   // compiler-only reorder fence

// ---------- pass 1: per-row symmetric int8 quant; w is packed into B-fragment layout ----------
// w-packed layout: P[c][kt][ni][ks][pos*16B], pos = kq*16 + r, holding row c*64+ni*16+r,
// k-bytes kt*128 + ks*64 + kq*16 .. +15. GEMM lane l (r16=l&15, kq=l>>4) reads pos=l ->
// LOADB is base + lane*16 (perfectly coalesced). Values bit-identical to r9's path.
__global__ __launch_bounds__(256)
void quant_rows(const float* __restrict__ x, const float* __restrict__ w,
                signed char* __restrict__ xq, signed char* __restrict__ wp,
                float* __restrict__ sx, float* __restrict__ sw,
                int Mrows, int totRows, int K) {
  __shared__ float red[4];
  for (int row = blockIdx.x; row < totRows; row += gridDim.x) {
    const bool isx = row < Mrows;
    const float* src = isx ? x + (size_t)row * K : w + (size_t)(row - Mrows) * K;
    const float4* s4 = reinterpret_cast<const float4*>(src) + threadIdx.x * 4;
    float4 v[4];
#pragma unroll
    for (int g = 0; g < 4; ++g) v[g] = s4[g];
    float am = 0.f;
#pragma unroll
    for (int g = 0; g < 4; ++g)
      am = fmaxf(am, fmaxf(fmaxf(fabsf(v[g].x), fabsf(v[g].y)),
                           fmaxf(fabsf(v[g].z), fabsf(v[g].w))));
#pragma unroll
    for (int m = 1; m <= 32; m <<= 1) am = fmaxf(am, __shfl_xor(am, m));
    if ((threadIdx.x & 63) == 0) red[threadIdx.x >> 6] = am;
    __syncthreads();
    am = fmaxf(fmaxf(red[0], red[1]), fmaxf(red[2], red[3]));
    const float s   = am > 0.f ? am * (1.f / 127.f) : 1.f;
    const float inv = am > 0.f ? 127.f / am : 0.f;
    u32 pk[4];
#pragma unroll
    for (int g = 0; g < 4; ++g) {
      const float* vp = reinterpret_cast<const float*>(&v[g]);
      u32 p = 0;
#pragma unroll
      for (int e = 0; e < 4; ++e) {
        int q = (int)rintf(vp[e] * inv);
        q = q < -127 ? -127 : (q > 127 ? 127 : q);
        p |= ((u32)(q & 0xff)) << (8 * e);
      }
      pk[g] = p;
    }
    const int t = threadIdx.x;
    signed char* dst;
    if (isx) {
      dst = xq + (size_t)row * K + t * 16;               // row-major (A path unchanged)
    } else {
      const int n  = row - Mrows;
      const int c  = n >> 6, ni = (n >> 4) & 3, r = n & 15;
      const int kt = t >> 3, ks = (t >> 2) & 1, kq = t & 3;
      dst = wp + ((((size_t)c * 32 + kt) * 4 + ni) * 2 + ks) * 1024 + (kq * 16 + r) * 16;
    }
    *reinterpret_cast<uint4*>(dst) = make_uint4(pk[0], pk[1], pk[2], pk[3]);
    if (t == 0) { if (isx) sx[row] = s; else sw[row - Mrows] = s; }
    __syncthreads();
  }
}

// ---------- pass 2: int8 GEMM BK=128, A in LDS (r9 path), B coalesced-packed from L2 ----------
// r9 structure with B off LDS: LDS wall 192->128 b128/CU-tile (2304->1536 cyc).
// LDS = A only [2][256*128] = 64 KiB, verified XOR swizzle (0 conflicts).
// B: 8 coalesced global_load_dwordx4 per wave per tile from the packed panel
// (1 MB per nt, L2-resident via nt-major XCD map), double-buffered in regs.
// r15 BUG FIX: the prologue mixed plain loads (LOADB, hoistable) with
// global_load_lds intrinsics without fences -> scheduler hoisted B loads above
// the stages, so vmcnt(12) no longer drained A(t0) -> tile0 consumed unlanded
// LDS (absmax 0.99 = 0xAA-garbage k-tile arithmetic). Fix: fence each prologue
// group, gate vmcnt(4) (drains B(t0)+A(t0), leaves A(t1) in flight) -> steady
// entry {A(t+1):4} reproduced exactly. In-loop regions were already fenced.
// Per tile (2 regions):
//  R1: LOADB(next,t+1) | rd afB(mh1k0) | C1=afA*B[k0] | rd afA(mh0k1) | C2=afB*B[k0]
//      | rd afB(mh1k1) | gate vmcnt(8) [drains A(t+1), staged t-1 R2] | BAR |
//  R2: stage A(t+2)->cur | C3=afA*B[k1] | rd afA<-A(t+1,mh0,k0) | C4=afB*B[k1]
//      | vmcnt(12) [no-op, doc] | BAR
// Ledger (steady): entry {B(t):8, A(t+1):4}; R1 +B(t+1) -> 20; compiler pre-C1
// wait drains B(t) (vmcnt<=12); gate vmcnt(8) drains A(t+1); R2 +A(t+2) -> 12.
__global__ __launch_bounds__(512, 2)
void gemm_i8_bpk(const signed char* __restrict__ A,   // [M][K] i8
                 const signed char* __restrict__ BP,  // packed B
                 const float* __restrict__ sx,        // [M]
                 const float* __restrict__ sw,        // [N]
                 const float* __restrict__ wscale_p,  // [1]
                 const float* __restrict__ bias,      // [N]
                 float* __restrict__ C,               // [M][N] fp32
                 int Nn, int Kk) {
  __shared__ signed char lds[2][256 * 128];   // A only, 64 KiB

  const int tid  = threadIdx.x;
  const int lane = tid & 63;
  const int wave = tid >> 6;       // 0..7
  const int wr = wave >> 2;        // 0..1 (M)
  const int wc = wave & 3;         // 0..3 (N)

  // nt-major XCD map: 32 concurrent wgs per XCD share ONE 1MB packed-B panel
  const int bid = blockIdx.x;
  const int xcd = bid & 7;
  const int j   = bid >> 3;        // 0..255
  const int nt  = xcd * 8 + (j >> 5);
  const int mt  = j & 31;
  const int m0 = mt * 256, n0 = nt * 256;

  // A staging: per gload instr, 64 lanes = 8 rows x 128B; lane l -> row l>>3, slot l&7
  const int srow = lane >> 3;
  const int ss   = (lane & 7) ^ (srow & 7);   // inverse-swizzled source k-slot
  const int r16  = lane & 15;
  const int kq   = lane >> 4;

  const signed char* ga = A + ((size_t)m0 + wave * 32 + srow) * Kk + ss * 16;
  // packed-B per-wave base: c = nt*4 + wc, stride 32 kt * 8192 = 256KB per c
  const signed char* pbw = BP + ((size_t)(nt * 4 + wc)) * 262144 + lane * 16;

  // A fragment byte offsets in LDS: row*128 + ((kq ^ (row&7))<<4); ks=1 flips bit 6
  const int aoff = (wr * 128 + r16) * 128 + ((kq ^ (r16 & 7)) << 4);

  i32x4 acc[8][4];
#pragma unroll
  for (int i = 0; i < 8; ++i)
#pragma unroll
    for (int jj = 0; jj < 4; ++jj)
      acc[i][jj] = (i32x4){0, 0, 0, 0};

  i32x4 afA[4], afB[4];    // A frags (mh roles, rotating ks)
  i32x4 bS0[8], bS1[8];    // B frag sets [0-3]=ks0, [4-7]=ks1; alternate by tile parity

#define STAGEA(bfi_, kt_) do {                                                  \
    const signed char* _g = ga + (size_t)(kt_) * 128;                           \
    signed char* _d = &lds[bfi_][wave * 32 * 128];                              \
    GLD_LDS16(_g,                    _d);                                       \
    GLD_LDS16(_g + (size_t)8  * Kk,  _d + 1024);                                \
    GLD_LDS16(_g + (size_t)16 * Kk,  _d + 2048);                                \
    GLD_LDS16(_g + (size_t)24 * Kk,  _d + 3072);                                \
  } while (0)

#define LOADB(SET_, kt_) do {                                                   \
    const signed char* _b = pbw + (size_t)(kt_) * 8192;                         \
    _Pragma("unroll") for (int _n = 0; _n < 4; ++_n) {                          \
      SET_[_n]     = *reinterpret_cast<const i32x4*>(_b + (_n * 2) * 1024);     \
      SET_[4 + _n] = *reinterpret_cast<const i32x4*>(_b + (_n * 2 + 1) * 1024); \
    } } while (0)

#define LDFA(AF_, la_, mh_, ks_) do {                                           \
    _Pragma("unroll") for (int _i = 0; _i < 4; ++_i)                            \
      AF_[_i] = *reinterpret_cast<const i32x4*>(                                \
          (la_) + ((aoff + ((mh_) * 4 + _i) * 2048) ^ ((ks_) << 6)));           \
  } while (0)

#define MFMAC(mh_, AF_, SET_, kb_)                                              \
  _Pragma("unroll") for (int _i = 0; _i < 4; ++_i)                              \
  _Pragma("unroll") for (int _n = 0; _n < 4; ++_n)                              \
    acc[(mh_) * 4 + _i][_n] = __builtin_amdgcn_mfma_i32_16x16x64_i8(            \
        AF_[_i], SET_[(kb_) * 4 + _n], acc[(mh_) * 4 + _i][_n], 0, 0, 0)

  const int KT = Kk >> 7;   // 32

  // ---- prologue (FENCED groups so plain loads cannot hoist across the ledger) ----
  LOADB(bS0, 0);                 // B(t0):8 -- issued FIRST (oldest)
  CFENCE();
  STAGEA(0, 0);                  // A(t0):4
  CFENCE();
  STAGEA(1, 1);                  // A(t1):4
  asm volatile("s_waitcnt vmcnt(4)" ::: "memory");  // drains B(t0)+A(t0); A(t1) flies
  SCHED0(); BAR(); SCHED0();
  LDFA(afA, (const signed char*)&lds[0][0], 0, 0);  // pre-read A(t0) mh0 ks0

#define TILE(t_, CUR_, CS_, NS_) do {                                           \
    const signed char* laC = &lds[CUR_][0];                                     \
    const signed char* laN = &lds[(CUR_) ^ 1][0];                               \
    const int kt1 = ((t_) + 1 < KT) ? (t_) + 1 : KT - 1;                        \
    const int kt2 = ((t_) + 2 < KT) ? (t_) + 2 : KT - 1;                        \
    /* R1 */                                                                    \
    LOADB(NS_, kt1);                          /* B(t+1) -> regs, coalesced */   \
    LDFA(afB, laC, 1, 0);                                                       \
    MFMAC(0, afA, CS_, 0);                    /* C1: mh0 ks0 */                 \
    LDFA(afA, laC, 0, 1);                                                       \
    MFMAC(1, afB, CS_, 0);                    /* C2: mh1 ks0 */                 \
    LDFA(afB, laC, 1, 1);                                                       \
    SCHED0();                                                                   \
    asm volatile("s_waitcnt vmcnt(8)" ::: "memory");   /* drains A(t+1) */      \
    SCHED0(); BAR(); SCHED0();                                                  \
    /* R2 */                                                                    \
    STAGEA(CUR_, kt2);                        /* A(t+2) -> cur */               \
    MFMAC(0, afA, CS_, 1);                    /* C3: mh0 ks1 */                 \
    LDFA(afA, laN, 0, 0);                     /* pre-read A(t+1) mh0 ks0 */     \
    MFMAC(1, afB, CS_, 1);                    /* C4: mh1 ks1 */                 \
    SCHED0();                                                                   \
    asm volatile("s_waitcnt vmcnt(12)" ::: "memory");  /* no-op by ledger; doc */ \
    SCHED0(); BAR(); SCHED0();                                                  \
  } while (0)

  for (int t = 0; t < KT; t += 2) {
    TILE(t,     0, bS0, bS1);
    TILE(t + 1, 1, bS1, bS0);
  }

  // ---- epilogue: out = acc * sx[row] * (sw[col]*wscale) + bias ----
  const float wsc = wscale_p[0];
  float cw[4], bv[4];
#pragma unroll
  for (int ni = 0; ni < 4; ++ni) {
    const int col = n0 + wc * 64 + ni * 16 + r16;
    cw[ni] = sw[col] * wsc;
    bv[ni] = bias[col];
  }
#pragma unroll
  for (int mi = 0; mi < 8; ++mi) {
#pragma unroll
    for (int r = 0; r < 4; ++r) {
      // C/D layout (16x16 shapes, dtype-independent): col = lane&15, row = (lane>>4)*4 + reg
      const int row = m0 + wr * 128 + mi * 16 + kq * 4 + r;
      const float sxr = sx[row];
      float* cp = C + (size_t)row * Nn + (n0 + wc * 64 + r16);
#pragma unroll
      for (int ni = 0; ni < 4; ++ni)
        cp[ni * 16] = (float)acc[mi][ni][r] * (sxr * cw[ni]) + bv[ni];
    }
  }
#undef STAGEA
#undef LOADB
#undef LDFA
#undef MFMAC
#undef TILE
}

extern "C" void kernel_launch(void* const* d_in, const int* in_sizes, int n_in,
                              void* d_out, int out_size, void* d_ws, size_t ws_size,
                              hipStream_t stream) {
  (void)n_in; (void)out_size; (void)ws_size;
  const float* x  = (const float*)d_in[0];   // [M][K] fp32
  const float* w  = (const float*)d_in[1];   // [N][K] fp32 (fp8-representable values)
  const float* sc = (const float*)d_in[2];   // [1]
  const float* bs = (const float*)d_in[3];   // [N]
  float* out = (float*)d_out;                // [M][N] fp32

  const int N = in_sizes[3];        // 16384
  const int K = in_sizes[1] / N;    // 4096
  const int M = in_sizes[0] / K;    // 8192

  signed char* xq = (signed char*)d_ws;            // [M][K] i8 row-major (32 MB)
  signed char* wp = xq + (size_t)M * K;            // packed B (64 MB)
  float* sxp = (float*)(wp + (size_t)N * K);       // [M]
  float* swp = sxp + M;                            // [N]

  quant_rows<<<M + N, 256, 0, stream>>>(x, w, xq, wp, sxp, swp, M, M + N, K);

  const int nwg = (M / 256) * (N / 256);           // 2048 = 8 XCD x 256
  gemm_i8_bpk<<<nwg, 512, 0, stream>>>(xq, wp, sxp, swp, sc, bs, out, N, K);
}

// Round 17
// 627.119 us; speedup vs baseline: 1.5876x; 1.2192x over previous
//
#include <hip/hip_runtime.h>
#include <stdint.h>

typedef unsigned int u32;
using i32x4 = __attribute__((ext_vector_type(4))) int;

// async global->LDS, 16B per lane, dest = wave-uniform base + lane*16
#define GLD_LDS16(SRC, DST)                                      \
  __builtin_amdgcn_global_load_lds(                              \
      (const __attribute__((address_space(1))) void*)(SRC),      \
      (__attribute__((address_space(3))) void*)(DST), 16, 0, 0)

#define SCHED0() __builtin_amdgcn_sched_barrier(0)
#define BAR()    __builtin_amdgcn_s_barrier()
#define PRIO(x)  __builtin_amdgcn_s_setprio(x)

// ---------- pass 1: per-row symmetric int8 quant (x rows, then w rows) ----------
__global__ __launch_bounds__(256)
void quant_rows(const float* __restrict__ x, const float* __restrict__ w,
                signed char* __restrict__ xq, signed char* __restrict__ wq,
                float* __restrict__ sx, float* __restrict__ sw,
                int Mrows, int totRows, int K) {
  __shared__ float red[4];
  for (int row = blockIdx.x; row < totRows; row += gridDim.x) {
    const bool isx = row < Mrows;
    const float* src = isx ? x + (size_t)row * K : w + (size_t)(row - Mrows) * K;
    const float4* s4 = reinterpret_cast<const float4*>(src) + threadIdx.x * 4;
    float4 v[4];
#pragma unroll
    for (int g = 0; g < 4; ++g) v[g] = s4[g];
    float am = 0.f;
#pragma unroll
    for (int g = 0; g < 4; ++g)
      am = fmaxf(am, fmaxf(fmaxf(fabsf(v[g].x), fabsf(v[g].y)),
                           fmaxf(fabsf(v[g].z), fabsf(v[g].w))));
#pragma unroll
    for (int m = 1; m <= 32; m <<= 1) am = fmaxf(am, __shfl_xor(am, m));
    if ((threadIdx.x & 63) == 0) red[threadIdx.x >> 6] = am;
    __syncthreads();
    am = fmaxf(fmaxf(red[0], red[1]), fmaxf(red[2], red[3]));
    const float s   = am > 0.f ? am * (1.f / 127.f) : 1.f;
    const float inv = am > 0.f ? 127.f / am : 0.f;
    u32 pk[4];
#pragma unroll
    for (int g = 0; g < 4; ++g) {
      const float* vp = reinterpret_cast<const float*>(&v[g]);
      u32 p = 0;
#pragma unroll
      for (int e = 0; e < 4; ++e) {
        int q = (int)rintf(vp[e] * inv);
        q = q < -127 ? -127 : (q > 127 ? 127 : q);
        p |= ((u32)(q & 0xff)) << (8 * e);
      }
      pk[g] = p;
    }
    signed char* dst = (isx ? xq + (size_t)row * K : wq + (size_t)(row - Mrows) * K)
                       + threadIdx.x * 16;
    *reinterpret_cast<uint4*>(dst) = make_uint4(pk[0], pk[1], pk[2], pk[3]);
    if (threadIdx.x == 0) { if (isx) sx[row] = s; else sw[row - Mrows] = s; }
    __syncthreads();
  }
}

// ---------- pass 2: int8 GEMM BK=128 (proven-best r9 structure, verbatim) ----------
// 256x256 tile, BK=128 (i8), 8 waves (2M x 4N), per-wave 128x64 = 8x4 16x16x64 frags,
// 64 MFMA/wave/K-tile in 4 clusters of 16 (mh0ks0, mh1ks0, mh0ks1, mh1ks1).
// LDS [2 buf][A/B][256 rows x 128B] = 128 KiB. Row = 128B = 8 slots of 16B; swizzle
// phys_slot = (ks*4+kq) ^ (row&7) (byte addr = base ^ (ks<<6)) -- 0-conflict verified.
// Staged via inverse-swizzled global source (global_load_lds writes linearly).
// 2 barriers + 1 vmcnt gate per BK=128 tile; every MFMA cluster's operands are
// ds_read >=1 cluster earlier; reads 12/12 per phase.
//   P0: BAR | rd afB(mh1,ks0) | C1=afA*bP | rd afA(mh0,ks1) | stage B(t+2)->cur
//       | C2=afB*bP | rd afB(mh1,ks1) | vmcnt(4)
//   P1: BAR | C3=afA*bQ | rd afA<-A(t+1,mh0,ks0), bP<-B(t+1,ks0) | stage A(t+2)->cur
//       | C4=afB*bQ | rd bQ<-B(t+1,ks1)   [bQ overwritten only after C4]
// Ledger: gate sees {B(t+1):4, A(t+1):4, B(t+2):4}; vmcnt(4) drains exactly the t+1
// data P1 pre-reads (issued >=1 phase earlier), leaves B(t+2) in flight.
__global__ __launch_bounds__(512, 2)
void gemm_i8_bk128(const signed char* __restrict__ A,   // [M][K] i8
                   const signed char* __restrict__ B,   // [N][K] i8
                   const float* __restrict__ sx,        // [M]
                   const float* __restrict__ sw,        // [N]
                   const float* __restrict__ wscale_p,  // [1]
                   const float* __restrict__ bias,      // [N]
                   float* __restrict__ C,               // [M][N] fp32
                   int Nn, int Kk, int NT) {
  __shared__ signed char lds[2][2][256 * 128];

  const int tid  = threadIdx.x;
  const int lane = tid & 63;
  const int wave = tid >> 6;       // 0..7
  const int wr = wave >> 2;        // 0..1 (M)
  const int wc = wave & 3;         // 0..3 (N)

  // T1: XCD-aware swizzle (gridDim.x == 2048, divisible by 8)
  const int bid = blockIdx.x;
  const int cpx = gridDim.x >> 3;
  const int wg  = (bid & 7) * cpx + (bid >> 3);
  const int mt = wg / NT, nt = wg % NT;
  const int m0 = mt * 256, n0 = nt * 256;

  // staging: per gload instr, 64 lanes = 8 rows x 128B; lane l -> row l>>3, slot l&7
  const int srow = lane >> 3;
  const int ss   = (lane & 7) ^ (srow & 7);   // inverse-swizzled source k-slot
  const int r16  = lane & 15;
  const int kq   = lane >> 4;

  // per-thread global staging bases (wave covers rows wave*32 .. +31, 4 gloads x 8 rows)
  const signed char* ga = A + ((size_t)m0 + wave * 32 + srow) * Kk + ss * 16;
  const signed char* gb = B + ((size_t)n0 + wave * 32 + srow) * Kk + ss * 16;

  // fragment byte offsets: row*128 + ((kq ^ (row&7))<<4); ks=1 flips byte bit 6
  const int aoff = (wr * 128 + r16) * 128 + ((kq ^ (r16 & 7)) << 4);
  const int boff = (wc * 64  + r16) * 128 + ((kq ^ (r16 & 7)) << 4);

  i32x4 acc[8][4];
#pragma unroll
  for (int i = 0; i < 8; ++i)
#pragma unroll
    for (int j = 0; j < 4; ++j)
      acc[i][j] = (i32x4){0, 0, 0, 0};

  i32x4 afA[4], afB[4];   // A frag sets (roles rotate across clusters)
  i32x4 bP[4], bQ[4];     // B frags ks0 / ks1

  // stage one operand tile (32KB, 4 gloads/wave): op (0=A,1=B) -> lds[bfi], k-tile kt
#define STAGE128(bfi_, op_, kt_) do {                                           \
    const signed char* _g = ((op_) ? gb : ga) + (size_t)(kt_) * 128;            \
    signed char* _d = &lds[bfi_][op_][wave * 32 * 128];                         \
    GLD_LDS16(_g,                    _d);                                       \
    GLD_LDS16(_g + (size_t)8  * Kk,  _d + 1024);                                \
    GLD_LDS16(_g + (size_t)16 * Kk,  _d + 2048);                                \
    GLD_LDS16(_g + (size_t)24 * Kk,  _d + 3072);                                \
  } while (0)

#define LDFA(AF_, la_, mh_, ks_) do {                                           \
    _Pragma("unroll") for (int _i = 0; _i < 4; ++_i)                            \
      AF_[_i] = *reinterpret_cast<const i32x4*>(                                \
          (la_) + ((aoff + ((mh_) * 4 + _i) * 2048) ^ ((ks_) << 6)));           \
  } while (0)

#define LDFB(BF_, lb_, ks_) do {                                                \
    _Pragma("unroll") for (int _n = 0; _n < 4; ++_n)                            \
      BF_[_n] = *reinterpret_cast<const i32x4*>(                                \
          (lb_) + ((boff + _n * 2048) ^ ((ks_) << 6)));                         \
  } while (0)

#define MFMAC(mh_, AF_, BF_)                                                    \
  _Pragma("unroll") for (int i = 0; i < 4; ++i)                                 \
  _Pragma("unroll") for (int n = 0; n < 4; ++n)                                 \
    acc[(mh_) * 4 + i][n] = __builtin_amdgcn_mfma_i32_16x16x64_i8(              \
        AF_[i], BF_[n], acc[(mh_) * 4 + i][n], 0, 0, 0)

  const int KT = Kk >> 7;   // K/128 = 32

  // ---- prologue: t0->buf0, t1->buf1 (A then B each); drain t0; pre-read t0 frags ----
  STAGE128(0, 0, 0); STAGE128(0, 1, 0);
  STAGE128(1, 0, 1); STAGE128(1, 1, 1);
  asm volatile("s_waitcnt vmcnt(8)" ::: "memory");
  SCHED0(); BAR(); SCHED0();
  LDFA(afA, (const signed char*)&lds[0][0][0], 0, 0);
  LDFB(bP,  (const signed char*)&lds[0][1][0], 0);
  LDFB(bQ,  (const signed char*)&lds[0][1][0], 1);

#define TILE128(t_, CUR_) do {                                                  \
    const signed char* laC = &lds[CUR_][0][0];                                  \
    const signed char* laN = &lds[(CUR_) ^ 1][0][0];                            \
    const signed char* lbN = &lds[(CUR_) ^ 1][1][0];                            \
    const int kt2 = ((t_) + 2 < KT) ? (t_) + 2 : KT - 1;                        \
    /* P0 */                                                                    \
    SCHED0(); BAR(); SCHED0();                                                  \
    LDFA(afB, laC, 1, 0);                                                       \
    PRIO(1); MFMAC(0, afA, bP); PRIO(0);      /* C1: mh0,ks0 */                 \
    LDFA(afA, laC, 0, 1);                                                       \
    STAGE128(CUR_, 1, kt2);                                                     \
    PRIO(1); MFMAC(1, afB, bP); PRIO(0);      /* C2: mh1,ks0 */                 \
    LDFA(afB, laC, 1, 1);                                                       \
    SCHED0();                                                                   \
    asm volatile("s_waitcnt vmcnt(4)" ::: "memory");                            \
    /* P1 */                                                                    \
    SCHED0(); BAR(); SCHED0();                                                  \
    PRIO(1); MFMAC(0, afA, bQ); PRIO(0);      /* C3: mh0,ks1 */                 \
    LDFA(afA, laN, 0, 0);                                                       \
    LDFB(bP, lbN, 0);                                                           \
    STAGE128(CUR_, 0, kt2);                                                     \
    PRIO(1); MFMAC(1, afB, bQ); PRIO(0);      /* C4: mh1,ks1 */                 \
    LDFB(bQ, lbN, 1);                         /* bQ dead only after C4 */       \
  } while (0)

  for (int t = 0; t < KT; t += 2) {
    TILE128(t,     0);
    TILE128(t + 1, 1);
  }

  // ---- epilogue: out = acc * sx[row] * (sw[col]*wscale) + bias ----
  const float wsc = wscale_p[0];
  float cw[4], bv[4];
#pragma unroll
  for (int ni = 0; ni < 4; ++ni) {
    const int col = n0 + wc * 64 + ni * 16 + r16;
    cw[ni] = sw[col] * wsc;
    bv[ni] = bias[col];
  }
#pragma unroll
  for (int mi = 0; mi < 8; ++mi) {
#pragma unroll
    for (int r = 0; r < 4; ++r) {
      // C/D layout (16x16 shapes, dtype-independent): col = lane&15, row = (lane>>4)*4 + reg
      const int row = m0 + wr * 128 + mi * 16 + kq * 4 + r;
      const float sxr = sx[row];
      float* cp = C + (size_t)row * Nn + (n0 + wc * 64 + r16);
#pragma unroll
      for (int ni = 0; ni < 4; ++ni)
        cp[ni * 16] = (float)acc[mi][ni][r] * (sxr * cw[ni]) + bv[ni];
    }
  }
#undef STAGE128
#undef LDFA
#undef LDFB
#undef MFMAC
#undef TILE128
}

extern "C" void kernel_launch(void* const* d_in, const int* in_sizes, int n_in,
                              void* d_out, int out_size, void* d_ws, size_t ws_size,
                              hipStream_t stream) {
  (void)n_in; (void)out_size; (void)ws_size;
  const float* x  = (const float*)d_in[0];   // [M][K] fp32
  const float* w  = (const float*)d_in[1];   // [N][K] fp32 (fp8-representable values)
  const float* sc = (const float*)d_in[2];   // [1]
  const float* bs = (const float*)d_in[3];   // [N]
  float* out = (float*)d_out;                // [M][N] fp32

  const int N = in_sizes[3];        // 16384
  const int K = in_sizes[1] / N;    // 4096
  const int M = in_sizes[0] / K;    // 8192

  signed char* xq = (signed char*)d_ws;            // [M][K] i8  (32 MB)
  signed char* wq = xq + (size_t)M * K;            // [N][K] i8  (64 MB)
  float* sxp = (float*)(wq + (size_t)N * K);       // [M]
  float* swp = sxp + M;                            // [N]

  quant_rows<<<M + N, 256, 0, stream>>>(x, w, xq, wq, sxp, swp, M, M + N, K);

  const int NT = N / 256;
  const int nwg = (M / 256) * NT;                  // 2048, % 8 == 0
  gemm_i8_bk128<<<nwg, 512, 0, stream>>>(xq, wq, sxp, swp, sc, bs, out, N, K, NT);
}